// Round 5
// baseline (232.686 us; speedup 1.0000x reference)
//
#include <hip/hip_runtime.h>
#include <hip/hip_bf16.h>

#define N_NODES 20000
#define M2 20224   // 79 * 256 padded rows

typedef __attribute__((ext_vector_type(8))) short short8;
typedef __attribute__((ext_vector_type(4))) float f32x4;

#define MFMA16(a,b,c) __builtin_amdgcn_mfma_f32_16x16x32_bf16(a,b,c,0,0,0)

static __device__ __forceinline__ ushort f2bf(float f) {
  union { float f; uint u; } v; v.f = f;
  uint u = v.u;
  uint r = (u + 0x7FFFu + ((u >> 16) & 1u)) >> 16;
  return (ushort)r;
}
static __device__ __forceinline__ float bf2f(ushort s) {
  union { uint u; float f; } v; v.u = ((uint)s) << 16; return v.f;
}

typedef __attribute__((address_space(1))) const unsigned int guint;
typedef __attribute__((address_space(3))) unsigned int luint;
static __device__ __forceinline__ void gl2lds16(const void* g, void* l) {
  __builtin_amdgcn_global_load_lds((guint*)g, (luint*)l, 16, 0, 0);
}

static __device__ __forceinline__ void cvt8(const float* __restrict__ s, ushort* __restrict__ d) {
  float4 v0 = *(const float4*)s;
  float4 v1 = *(const float4*)(s + 4);
  union { ushort u[8]; uint4 v; } t;
  t.u[0]=f2bf(v0.x); t.u[1]=f2bf(v0.y); t.u[2]=f2bf(v0.z); t.u[3]=f2bf(v0.w);
  t.u[4]=f2bf(v1.x); t.u[5]=f2bf(v1.y); t.u[6]=f2bf(v1.z); t.u[7]=f2bf(v1.w);
  *(uint4*)d = t.v;
}

// ---------------- K0: prep — inputs/weights -> bf16, Bgru build, deg=0 ----------------
__global__ __launch_bounds__(256) void k_prep(
    const float* __restrict__ x, const float* __restrict__ h,
    const float* __restrict__ Wfc, const float* __restrict__ Wc,
    const float* __restrict__ Wih, const float* __restrict__ Whh,
    ushort* __restrict__ xB, ushort* __restrict__ hB,
    ushort* __restrict__ WfcB, ushort* __restrict__ WcTB,
    ushort* __restrict__ Bgru, int* __restrict__ deg) {
  int i = blockIdx.x * 256 + threadIdx.x;
  if (i < 640000) {            // x,h: 20000*256/8
    int off = i * 8;
    cvt8(x + off, xB + off);
    cvt8(h + off, hB + off);
  }
  if (i < 16384) { int off = i * 8; cvt8(Wfc + off, WfcB + off); }
  if (i < 65536) { int c = i >> 8, k = i & 255; WcTB[c*256 + k] = f2bf(Wc[k*256 + c]); }
  if (i < 65536) {
    // Bgru[1024][512]: row = g*64 + p*16 + ci  (c = g*16+ci), 8 elems per thread
    int row = i >> 6;
    int k0 = (i & 63) * 8;
    int p = (row >> 4) & 3;
    int c = ((row >> 6) << 4) + (row & 15);
    bool lo = k0 < 256;
    ushort outv[8];
    #pragma unroll
    for (int e = 0; e < 8; ++e) {
      int k = k0 + e;
      float v;
      if (p == 0)      v = lo ? Wih[(size_t)c*256 + k]        : Whh[(size_t)c*256 + k - 256];
      else if (p == 1) v = lo ? Wih[(size_t)(256+c)*256 + k]  : Whh[(size_t)(256+c)*256 + k - 256];
      else if (p == 2) v = lo ? Wih[(size_t)(512+c)*256 + k]  : 0.f;
      else             v = lo ? 0.f : Whh[(size_t)(512+c)*256 + k - 256];
      outv[e] = f2bf(v);
    }
    *(uint4*)&Bgru[(size_t)row*512 + k0] = *(uint4*)outv;
  }
  if (i < N_NODES) deg[i] = 0;
}

// ---------------- B-stationary GEMM: barrier-free K loop ----------------
// C[r][c] = sum_k A(r,k)*B[c][k].  K = NPH*256; phase p uses A=Ap, B k-cols [p*256,..).
// Block: 256 thr = 4 waves x 64 rows (BM=256); BN=64 B-rows in LDS (XOR-swizzled).
// EPI: 0 plain bf16, 1 bias+relu bf16, 2 fused GRU f32 (BN = 4 planes x 16 cols).
template<int NPH, int EPI>
__global__ __launch_bounds__(256, 3) void k_bsta(
    const ushort* __restrict__ A0, const ushort* __restrict__ A1,
    const ushort* __restrict__ B, ushort* __restrict__ Cb,
    float* __restrict__ Cf, const float* __restrict__ bias,
    const float* __restrict__ bih, const float* __restrict__ bhh,
    const ushort* __restrict__ xrg) {
  __shared__ __attribute__((aligned(16))) ushort sB[64 * 256];
  const int ldb = NPH * 256;
  int col0 = blockIdx.x * 64;          // x fastest: consecutive blocks share A rows
  int row0 = blockIdx.y * 256;
  int t = threadIdx.x, w = t >> 6, l = t & 63;
  int arow = row0 + w * 64 + (l & 15);
  f32x4 acc[4][4] = {};
  const ushort* APH[2] = {A0, A1};
  #pragma unroll
  for (int ph = 0; ph < NPH; ++ph) {
    if (ph) __syncthreads();
    // stage B half [64 rows][256 k]: LDS chunk ci holds global word16 (ci&31)^(row&7)
    #pragma unroll
    for (int j = 0; j < 8; ++j) {
      int ci = j * 256 + t;
      int br = ci >> 5;
      int gw = (ci & 31) ^ (br & 7);
      gl2lds16(B + (size_t)(col0 + br) * ldb + ph * 256 + gw * 8,
               (char*)sB + (size_t)(j * 256 + w * 64) * 16);
    }
    __syncthreads();
    const ushort* Ap = APH[ph];
    #pragma unroll
    for (int ks = 0; ks < 8; ++ks) {
      int k0 = ks * 32;
      short8 af[4], bfr[4];
      #pragma unroll
      for (int mi = 0; mi < 4; ++mi)
        af[mi] = *(const short8*)(Ap + (size_t)(arow + mi * 16) * 256 + k0 + (l >> 4) * 8);
      #pragma unroll
      for (int ni = 0; ni < 4; ++ni) {
        int br = ni * 16 + (l & 15);
        int k16 = (ks * 4 + (l >> 4)) ^ (br & 7);
        bfr[ni] = *(const short8*)&sB[br * 256 + k16 * 8];
      }
      #pragma unroll
      for (int mi = 0; mi < 4; ++mi)
        #pragma unroll
        for (int ni = 0; ni < 4; ++ni)
          acc[mi][ni] = MFMA16(af[mi], bfr[ni], acc[mi][ni]);
    }
  }
  int lq = (l >> 4) * 4;
  if (EPI == 2) {
    int c = blockIdx.x * 16 + (l & 15);
    float br_ = bih[c] + bhh[c];
    float bz_ = bih[256 + c] + bhh[256 + c];
    float bi_ = bih[512 + c];
    float bh_ = bhh[512 + c];
    #pragma unroll
    for (int mi = 0; mi < 4; ++mi)
      #pragma unroll
      for (int q = 0; q < 4; ++q) {
        int r = row0 + w * 64 + mi * 16 + lq + q;
        if (r < N_NODES) {
          float rg = 1.f / (1.f + __expf(-(acc[mi][0][q] + br_)));
          float zg = 1.f / (1.f + __expf(-(acc[mi][1][q] + bz_)));
          float ng = tanhf((acc[mi][2][q] + bi_) + rg * (acc[mi][3][q] + bh_));
          float xv = bf2f(xrg[(size_t)r * 256 + c]);
          Cf[(size_t)r * 256 + c] = (1.f - zg) * ng + zg * xv;
        }
      }
  } else {
    #pragma unroll
    for (int mi = 0; mi < 4; ++mi)
      #pragma unroll
      for (int ni = 0; ni < 4; ++ni)
        #pragma unroll
        for (int q = 0; q < 4; ++q) {
          int r = row0 + w * 64 + mi * 16 + lq + q;
          int c = col0 + ni * 16 + (l & 15);
          if (r < N_NODES) {
            float v = acc[mi][ni][q];
            if (EPI == 1) { v += bias[c]; v = v > 0.f ? v : 0.f; }
            Cb[(size_t)r * 256 + c] = f2bf(v);
          }
        }
  }
}

// ---------------- CSR build ----------------
__global__ __launch_bounds__(256) void k_hist(const int* __restrict__ eg, int* __restrict__ deg) {
  int e = blockIdx.x * 256 + threadIdx.x;
  if (e < 320000) atomicAdd(&deg[eg[320000 + e]], 1);
}

__global__ __launch_bounds__(256) void k_scan(const int* __restrict__ deg,
                                              int* __restrict__ offs, int* __restrict__ cursor) {
  __shared__ int part[256];
  int t = threadIdx.x;
  const int CH = 79;
  int base = t * CH;
  int s = 0;
  for (int i = 0; i < CH; i++) { int idx = base + i; if (idx < N_NODES) s += deg[idx]; }
  part[t] = s; __syncthreads();
  for (int d = 1; d < 256; d <<= 1) {
    int v = (t >= d) ? part[t - d] : 0;
    __syncthreads();
    part[t] += v;
    __syncthreads();
  }
  int run = (t == 0) ? 0 : part[t - 1];
  for (int i = 0; i < CH; i++) {
    int idx = base + i;
    if (idx < N_NODES) { offs[idx] = run; cursor[idx] = run; run += deg[idx]; }
  }
}

__global__ __launch_bounds__(256) void k_bucket(const int* __restrict__ eg,
                                                int* __restrict__ cursor, int* __restrict__ srcs) {
  int e = blockIdx.x * 256 + threadIdx.x;
  if (e < 320000) {
    int d = eg[320000 + e];
    int slot = atomicAdd(&cursor[d], 1);
    srcs[slot] = eg[e];
  }
}

// ---------------- gather-reduce agg[n] = sum m[src] ----------------
__global__ __launch_bounds__(256) void k_agg(
    const int* __restrict__ offs, const int* __restrict__ deg, const int* __restrict__ srcs,
    const ushort* __restrict__ m, ushort* __restrict__ agg) {
  int node = blockIdx.x * 8 + (threadIdx.x >> 5);
  if (node >= N_NODES) return;
  int lane = threadIdx.x & 31;
  int off = offs[node];
  int n = deg[node];
  float a[8] = {};
  int i = 0;
  for (; i + 4 <= n; i += 4) {
    uint4 v0 = *(const uint4*)(m + (size_t)srcs[off+i  ] * 256 + lane * 8);
    uint4 v1 = *(const uint4*)(m + (size_t)srcs[off+i+1] * 256 + lane * 8);
    uint4 v2 = *(const uint4*)(m + (size_t)srcs[off+i+2] * 256 + lane * 8);
    uint4 v3 = *(const uint4*)(m + (size_t)srcs[off+i+3] * 256 + lane * 8);
    const ushort* p0 = (const ushort*)&v0; const ushort* p1 = (const ushort*)&v1;
    const ushort* p2 = (const ushort*)&v2; const ushort* p3 = (const ushort*)&v3;
    #pragma unroll
    for (int j = 0; j < 8; j++) a[j] += (bf2f(p0[j]) + bf2f(p1[j])) + (bf2f(p2[j]) + bf2f(p3[j]));
  }
  for (; i < n; ++i) {
    uint4 v0 = *(const uint4*)(m + (size_t)srcs[off+i] * 256 + lane * 8);
    const ushort* p0 = (const ushort*)&v0;
    #pragma unroll
    for (int j = 0; j < 8; j++) a[j] += bf2f(p0[j]);
  }
  union { ushort s[8]; uint4 v; } o;
  #pragma unroll
  for (int j = 0; j < 8; j++) o.s[j] = f2bf(a[j]);
  *(uint4*)(agg + (size_t)node * 256 + lane * 8) = o.v;
}

extern "C" void kernel_launch(void* const* d_in, const int* in_sizes, int n_in,
                              void* d_out, int out_size, void* d_ws, size_t ws_size,
                              hipStream_t stream) {
  const float* h   = (const float*)d_in[0];
  const float* x   = (const float*)d_in[1];
  const float* Wfc = (const float*)d_in[3];
  const float* bfc = (const float*)d_in[4];
  const float* Wc  = (const float*)d_in[5];
  const float* Wih = (const float*)d_in[6];
  const float* Whh = (const float*)d_in[7];
  const float* bih = (const float*)d_in[8];
  const float* bhh = (const float*)d_in[9];
  const int*   eg  = (const int*)d_in[10];
  float* out = (float*)d_out;

  char* ws = (char*)d_ws;
  // M2*256*2 = 10,354,688 per [M][256] bf16 buffer
  ushort* xr   = (ushort*)(ws);                  // live to the end
  ushort* xB   = (ushort*)(ws + 10354688);       // dead after fc
  ushort* m    = (ushort*)(ws + 10354688);       // conv out — aliases xB
  ushort* hB   = (ushort*)(ws + 20709376);       // dead after fc
  ushort* agg  = (ushort*)(ws + 20709376);       // aliases hB
  ushort* WfcB = (ushort*)(ws + 31064064);       //   262,144
  ushort* WcTB = (ushort*)(ws + 31326208);       //   131,072
  ushort* Bgru = (ushort*)(ws + 31457280);       // 1,048,576
  int*    deg    = (int*)(ws + 32505856);        //    80,000
  int*    offs   = (int*)(ws + 32585856);
  int*    cursor = (int*)(ws + 32665856);
  int*    srcs   = (int*)(ws + 32745856);        // 1,280,000 -> total ~34.0 MB

  k_prep<<<2500, 256, 0, stream>>>(x, h, Wfc, Wc, Wih, Whh,
                                   xB, hB, WfcB, WcTB, Bgru, deg);

  // fc: xr = relu([x|h] @ Wfc^T + b)
  k_bsta<2,1><<<dim3(4,79), 256, 0, stream>>>(xB, hB, WfcB, xr, nullptr, bfc,
                                              nullptr, nullptr, nullptr);
  // conv: m = xr @ WcT^T
  k_bsta<1,0><<<dim3(4,79), 256, 0, stream>>>(xr, xr, WcTB, m, nullptr, nullptr,
                                              nullptr, nullptr, nullptr);

  int eb = (320000 + 255) / 256;
  k_hist<<<eb, 256, 0, stream>>>(eg, deg);
  k_scan<<<1, 256, 0, stream>>>(deg, offs, cursor);
  k_bucket<<<eb, 256, 0, stream>>>(eg, cursor, srcs);
  k_agg<<<(N_NODES + 7) / 8, 256, 0, stream>>>(offs, deg, srcs, m, agg);

  // gru: out = GRU(agg, xr) via Bgru[1024][512] (planes interleaved per 16 cols)
  k_bsta<2,2><<<dim3(16,79), 256, 0, stream>>>(agg, xr, Bgru, nullptr, out, nullptr,
                                               bih, bhh, xr);
}